// Round 4
// baseline (222.374 us; speedup 1.0000x reference)
//
#include <hip/hip_runtime.h>
#include <stdint.h>

#define NB 1024
#define BB 256
#define KK 16
#define HH 64
#define WW 64
#define F_FULL 144
#define HDIM 128
#define CDIM 16
#define KPAD 160
#define APITCH 168   // A LDS pitch (bf16 elems) — 336 B rows: 2-way bank alias only (free)
#define HPITCH 136   // h LDS pitch (bf16 elems)

typedef __bf16 bf16x8 __attribute__((ext_vector_type(8)));
typedef float f32x4 __attribute__((ext_vector_type(4)));

// ---------------- ws layout ----------------
// [0,4)        : int err_count
// [4,8)        : int done_count
// [256, ..)    : W1t bf16 [16][128][160]  (drop-shifted, h-major, k-contig, k>=144 zero)
// [.., ..)     : W2b bf16 [16][128]       (c-major, k-contig)
// [.., ..)     : zt u8 (H,W,B,K)
#define W1T_OFF 256
#define W1T_BYTES (16 * HDIM * KPAD * 2)
#define W2B_OFF (W1T_OFF + W1T_BYTES)
#define W2B_BYTES (CDIM * HDIM * 2)
#define ZT_OFF (W2B_OFF + W2B_BYTES)

__device__ __forceinline__ unsigned short bf16_bits(float v) {
    __bf16 b = (__bf16)v;
    return __builtin_bit_cast(unsigned short, b);
}

// Fused prep: blocks [0,4096) transpose z -> zt ; [4096,5376) build W1t ;
// [5376,5384) build W2b ; block 5376 t==0 zeroes counters.
#define TP 144
__global__ __launch_bounds__(256) void prep_kernel(
    const int* __restrict__ z, const float* __restrict__ W1,
    const float* __restrict__ W2, uint8_t* __restrict__ zt,
    unsigned short* __restrict__ W1t, unsigned short* __restrict__ W2b,
    int* __restrict__ counters) {
    int bid = blockIdx.x;
    int t = threadIdx.x;
    if (bid < 4096) {
        // Transpose z (B,K,H,W) i32 -> zt u8 (H,W,B,K).
        // As 4096x4096: In[r=b*16+k][c=h*64+w] -> Out[c][r]. Tile: 128 r x 32 c.
        __shared__ uint8_t tile[32 * TP];   // tile[c][r], pitch 144
        int bx = bid & 127;                 // c tile
        int by = bid >> 7;                  // r tile, 0..31
        int c0 = bx * 32, r0 = by * 128;
#pragma unroll
        for (int i = 0; i < 4; ++i) {
            int lin = i * 256 + t;
            int c = lin & 31;
            int rq = lin >> 5;
            uchar4 v;
            v.x = (uint8_t)z[(size_t)(r0 + rq * 4 + 0) * 4096 + c0 + c];
            v.y = (uint8_t)z[(size_t)(r0 + rq * 4 + 1) * 4096 + c0 + c];
            v.z = (uint8_t)z[(size_t)(r0 + rq * 4 + 2) * 4096 + c0 + c];
            v.w = (uint8_t)z[(size_t)(r0 + rq * 4 + 3) * 4096 + c0 + c];
            *(uchar4*)(tile + c * TP + rq * 4) = v;
        }
        __syncthreads();
        int cy = t >> 3, rx = t & 7;
        uint4 v = *(const uint4*)(tile + cy * TP + rx * 16);
        *(uint4*)(zt + (size_t)(c0 + cy) * 4096 + r0 + rx * 16) = v;
    } else if (bid < 5376) {
        int idx = (bid - 4096) * 256 + t;   // 16*128*160 = 327680
        int k = idx % KPAD;
        int h = (idx / KPAD) % HDIM;
        int s = idx / (KPAD * HDIM);
        int drop = 4 * KK + s;
        float val = 0.0f;
        if (k < F_FULL && k != drop) {
            int src = k - (k > drop ? 1 : 0);
            val = W1[src * HDIM + h];
        }
        W1t[idx] = bf16_bits(val);
    } else {
        int idx = (bid - 5376) * 256 + t;   // 2048 total
        if (idx < CDIM * HDIM) {
            int k = idx % HDIM;
            int c = idx / HDIM;
            W2b[idx] = bf16_bits(W2[k * CDIM + c]);
        }
        if (bid == 5376 && t == 0) { counters[0] = 0; counters[1] = 0; }
    }
}

// Main fused MFMA kernel: one block = (n, 64-wide b tile), 4 waves.
// LDS overlay: sA [64][168] bf16 (21504 B) / sH [64][136] bf16 (17408 B, same base)
//              slg [64][17] f32 at byte 17408 -> total 21760 B -> 7 blocks/CU
__global__ __launch_bounds__(256, 4) void main_kernel(
    const uint8_t* __restrict__ zt, const unsigned short* __restrict__ W1t,
    const float* __restrict__ b1, const unsigned short* __restrict__ W2b,
    const float* __restrict__ b2, const int* __restrict__ bs,
    const int* __restrict__ ii, const int* __restrict__ jj,
    int* __restrict__ counters, float* __restrict__ out) {
    __shared__ __align__(16) unsigned char smem[21760];
    unsigned short* sA = (unsigned short*)smem;           // [64][APITCH]
    unsigned short* sH = (unsigned short*)smem;           // [64][HPITCH]
    float* slg = (float*)(smem + 64 * HPITCH * 2);        // [64][17]

    int t = threadIdx.x;
    int bid = blockIdx.x;
    int n = bid >> 2;
    int b_base = (bid & 3) << 6;
    int wave = t >> 6, lane = t & 63;
    int l15 = lane & 15, l4 = lane >> 4;

    int in_ = ii[n], jn = jj[n], sn = bs[n];

    // ---- zero A pad region k in [144,168) ----
    if (t < 192) {
        int b = t / 3, part = t % 3;
        *(uint4*)(sA + b * APITCH + F_FULL + part * 8) = make_uint4(0, 0, 0, 0);
    }

    // ---- B fragments (registers, L2-hot global loads) ----
    const unsigned short* w1s = W1t + (size_t)sn * (HDIM * KPAD);
    int n0 = wave * 32;
    bf16x8 Bf[2][5];
#pragma unroll
    for (int nt = 0; nt < 2; ++nt)
#pragma unroll
        for (int ks = 0; ks < 5; ++ks)
            Bf[nt][ks] = *(const bf16x8*)(w1s + (n0 + nt * 16 + l15) * KPAD + ks * 32 + l4 * 8);
    bf16x8 Bf2[4];
#pragma unroll
    for (int ks = 0; ks < 4; ++ks)
        Bf2[ks] = *(const bf16x8*)(W2b + l15 * HDIM + ks * 32 + l4 * 8);
    float b1v0 = b1[n0 + l15], b1v1 = b1[n0 + 16 + l15];
    float b2v = b2[l15];

    // ---- stage ctx -> sA bf16: 9 pixels x 64 b x 16 k ----
    for (int item = t; item < 9 * 64; item += 256) {
        int p = item >> 6;
        int b = item & 63;
        int di = p / 3 - 1, dj = p % 3 - 1;
        int ni = (in_ + di + HH) & (HH - 1);
        int nj = (jn + dj + WW) & (WW - 1);
        const uint8_t* src = zt + (((size_t)(ni * WW + nj) * BB + (b_base + b)) << 4);
        uint4 raw = *(const uint4*)src;
        const uint8_t* bytes = (const uint8_t*)&raw;
        union { __bf16 h[16]; uint4 q[2]; } u;
#pragma unroll
        for (int k = 0; k < 16; ++k)
            u.h[k] = (__bf16)((float)bytes[k] * (1.0f / 15.0f));
        uint4* dst = (uint4*)(sA + b * APITCH + p * 16);
        dst[0] = u.q[0];
        dst[1] = u.q[1];
    }
    __syncthreads();

    // ---- GEMM1: M=64 x N=128 x K=160, wave owns 32 N-cols, 4 M-tiles ----
    f32x4 acc[4][2] = {};
#pragma unroll
    for (int mt = 0; mt < 4; ++mt) {
        bf16x8 Af[5];
#pragma unroll
        for (int ks = 0; ks < 5; ++ks)
            Af[ks] = *(const bf16x8*)(sA + (mt * 16 + l15) * APITCH + ks * 32 + l4 * 8);
#pragma unroll
        for (int ks = 0; ks < 5; ++ks) {
            acc[mt][0] = __builtin_amdgcn_mfma_f32_16x16x32_bf16(Af[ks], Bf[0][ks], acc[mt][0], 0, 0, 0);
            acc[mt][1] = __builtin_amdgcn_mfma_f32_16x16x32_bf16(Af[ks], Bf[1][ks], acc[mt][1], 0, 0, 0);
        }
    }
    __syncthreads();   // all sA reads done before sH overlay writes

    // ---- bias + relu -> sH bf16 [b][h] ----
#pragma unroll
    for (int mt = 0; mt < 4; ++mt)
#pragma unroll
        for (int nt = 0; nt < 2; ++nt) {
            float bv = nt ? b1v1 : b1v0;
            int hcol = n0 + nt * 16 + l15;
#pragma unroll
            for (int r = 0; r < 4; ++r) {
                int b = mt * 16 + l4 * 4 + r;
                float v = fmaxf(acc[mt][nt][r] + bv, 0.0f);
                sH[b * HPITCH + hcol] = bf16_bits(v);
            }
        }
    __syncthreads();

    // ---- GEMM2: M=64 x N=16 x K=128; wave owns M-tile `wave` ----
    f32x4 acc2 = {};
#pragma unroll
    for (int ks = 0; ks < 4; ++ks) {
        bf16x8 Af = *(const bf16x8*)(sH + (wave * 16 + l15) * HPITCH + ks * 32 + l4 * 8);
        acc2 = __builtin_amdgcn_mfma_f32_16x16x32_bf16(Af, Bf2[ks], acc2, 0, 0, 0);
    }
#pragma unroll
    for (int r = 0; r < 4; ++r) {
        int b = wave * 16 + l4 * 4 + r;
        slg[b * 17 + l15] = acc2[r] + b2v;
    }
    __syncthreads();

    // ---- argmax + compare + ballot (wave 0) ----
    if (t < 64) {
        float best = slg[t * 17];
        int pi = 0;
#pragma unroll
        for (int c = 1; c < CDIM; ++c) {
            float v = slg[t * 17 + c];
            if (v > best) { best = v; pi = c; }   // strict > = first-max (jnp.argmax)
        }
        int tgt = zt[(((size_t)(in_ * WW + jn) * BB + b_base + t) << 4) + sn];
        unsigned long long m = __ballot(pi != tgt);
        if (t == 0) atomicAdd(&counters[0], (int)__popcll(m));
    }

    // ---- last block finalizes (device-scope release via threadfence) ----
    if (t == 0) {
        __threadfence();
        int old = atomicAdd(&counters[1], 1);
        if (old == NB * 4 - 1) {
            int total = atomicAdd(&counters[0], 0);   // coherent read
            out[0] = (float)total / (float)(NB * BB);
        }
    }
}

extern "C" void kernel_launch(void* const* d_in, const int* in_sizes, int n_in,
                              void* d_out, int out_size, void* d_ws, size_t ws_size,
                              hipStream_t stream) {
    const int* z = (const int*)d_in[0];
    const int* bs = (const int*)d_in[1];
    const int* ii = (const int*)d_in[2];
    const int* jj = (const int*)d_in[3];
    const float* W1 = (const float*)d_in[4];
    const float* b1 = (const float*)d_in[5];
    const float* W2 = (const float*)d_in[6];
    const float* b2 = (const float*)d_in[7];
    float* out = (float*)d_out;

    uint8_t* ws = (uint8_t*)d_ws;
    int* counters = (int*)ws;
    unsigned short* W1t = (unsigned short*)(ws + W1T_OFF);
    unsigned short* W2b = (unsigned short*)(ws + W2B_OFF);
    uint8_t* zt = ws + ZT_OFF;

    prep_kernel<<<5384, 256, 0, stream>>>(z, W1, W2, zt, W1t, W2b, counters);
    main_kernel<<<NB * 4, 256, 0, stream>>>(zt, W1t, b1, W2b, b2, bs, ii, jj, counters, out);
}

// Round 5
// 162.424 us; speedup vs baseline: 1.3691x; 1.3691x over previous
//
#include <hip/hip_runtime.h>
#include <stdint.h>

#define NB 1024
#define BB 256
#define KK 16
#define HH 64
#define WW 64
#define F_FULL 144
#define HDIM 128
#define CDIM 16
#define KPAD 160
#define APITCH 168   // A LDS pitch (bf16 elems) — 336 B rows
#define HPITCH 136   // h LDS pitch (bf16 elems)

typedef __bf16 bf16x8 __attribute__((ext_vector_type(8)));
typedef float f32x4 __attribute__((ext_vector_type(4)));

// ---------------- ws layout ----------------
// [0,4)        : int err_count
// [256, ..)    : W1t bf16 [16][128][160]
// [.., ..)     : W2b bf16 [16][128]
// [.., ..)     : zt u8 (H,W,B,K)
#define W1T_OFF 256
#define W1T_BYTES (16 * HDIM * KPAD * 2)
#define W2B_OFF (W1T_OFF + W1T_BYTES)
#define W2B_BYTES (CDIM * HDIM * 2)
#define ZT_OFF (W2B_OFF + W2B_BYTES)

__device__ __forceinline__ unsigned short bf16_bits(float v) {
    __bf16 b = (__bf16)v;
    return __builtin_bit_cast(unsigned short, b);
}

// Fused prep: blocks [0,4096) transpose z -> zt ; [4096,5376) build W1t ;
// [5376,5384) build W2b ; block 5376 t==0 zeroes err counter.
#define TP 144
__global__ __launch_bounds__(256) void prep_kernel(
    const int* __restrict__ z, const float* __restrict__ W1,
    const float* __restrict__ W2, uint8_t* __restrict__ zt,
    unsigned short* __restrict__ W1t, unsigned short* __restrict__ W2b,
    int* __restrict__ counters) {
    int bid = blockIdx.x;
    int t = threadIdx.x;
    if (bid < 4096) {
        __shared__ uint8_t tile[32 * TP];   // tile[c][r], pitch 144
        int bx = bid & 127;                 // c tile
        int by = bid >> 7;                  // r tile, 0..31
        int c0 = bx * 32, r0 = by * 128;
#pragma unroll
        for (int i = 0; i < 4; ++i) {
            int lin = i * 256 + t;
            int c = lin & 31;
            int rq = lin >> 5;
            uchar4 v;
            v.x = (uint8_t)z[(size_t)(r0 + rq * 4 + 0) * 4096 + c0 + c];
            v.y = (uint8_t)z[(size_t)(r0 + rq * 4 + 1) * 4096 + c0 + c];
            v.z = (uint8_t)z[(size_t)(r0 + rq * 4 + 2) * 4096 + c0 + c];
            v.w = (uint8_t)z[(size_t)(r0 + rq * 4 + 3) * 4096 + c0 + c];
            *(uchar4*)(tile + c * TP + rq * 4) = v;
        }
        __syncthreads();
        int cy = t >> 3, rx = t & 7;
        uint4 v = *(const uint4*)(tile + cy * TP + rx * 16);
        *(uint4*)(zt + (size_t)(c0 + cy) * 4096 + r0 + rx * 16) = v;
    } else if (bid < 5376) {
        int idx = (bid - 4096) * 256 + t;   // 16*128*160 = 327680
        int k = idx % KPAD;
        int h = (idx / KPAD) % HDIM;
        int s = idx / (KPAD * HDIM);
        int drop = 4 * KK + s;
        float val = 0.0f;
        if (k < F_FULL && k != drop) {
            int src = k - (k > drop ? 1 : 0);
            val = W1[src * HDIM + h];
        }
        W1t[idx] = bf16_bits(val);
    } else {
        int idx = (bid - 5376) * 256 + t;   // 2048 total
        if (idx < CDIM * HDIM) {
            int k = idx % HDIM;
            int c = idx / HDIM;
            W2b[idx] = bf16_bits(W2[k * CDIM + c]);
        }
        if (bid == 5376 && t == 0) counters[0] = 0;
    }
}

// Main fused MFMA kernel: one block = (n, 64-wide b tile), 4 waves.
// LDS overlay: sA [64][168] bf16 (21504 B) / sH [64][136] bf16 (same base)
//              slg [64][17] f32 at byte 17408 -> total 21760 B -> 7 blocks/CU
__global__ __launch_bounds__(256, 3) void main_kernel(
    const uint8_t* __restrict__ zt, const unsigned short* __restrict__ W1t,
    const float* __restrict__ b1, const unsigned short* __restrict__ W2b,
    const float* __restrict__ b2, const int* __restrict__ bs,
    const int* __restrict__ ii, const int* __restrict__ jj,
    int* __restrict__ counters) {
    __shared__ __align__(16) unsigned char smem[21760];
    unsigned short* sA = (unsigned short*)smem;           // [64][APITCH]
    unsigned short* sH = (unsigned short*)smem;           // [64][HPITCH]
    float* slg = (float*)(smem + 64 * HPITCH * 2);        // [64][17]

    int t = threadIdx.x;
    int bid = blockIdx.x;
    int n = bid >> 2;
    int b_base = (bid & 3) << 6;
    int wave = t >> 6, lane = t & 63;
    int l15 = lane & 15, l4 = lane >> 4;

    int in_ = ii[n], jn = jj[n], sn = bs[n];

    // ---- zero A pad region k in [144,168) ----
    if (t < 192) {
        int b = t / 3, part = t % 3;
        *(uint4*)(sA + b * APITCH + F_FULL + part * 8) = make_uint4(0, 0, 0, 0);
    }

    // ---- B fragments (registers, L2-hot global loads) ----
    const unsigned short* w1s = W1t + (size_t)sn * (HDIM * KPAD);
    int n0 = wave * 32;
    bf16x8 Bf[2][5];
#pragma unroll
    for (int nt = 0; nt < 2; ++nt)
#pragma unroll
        for (int ks = 0; ks < 5; ++ks)
            Bf[nt][ks] = *(const bf16x8*)(w1s + (n0 + nt * 16 + l15) * KPAD + ks * 32 + l4 * 8);
    bf16x8 Bf2[4];
#pragma unroll
    for (int ks = 0; ks < 4; ++ks)
        Bf2[ks] = *(const bf16x8*)(W2b + l15 * HDIM + ks * 32 + l4 * 8);
    float b1v0 = b1[n0 + l15], b1v1 = b1[n0 + 16 + l15];
    float b2v = b2[l15];

    // ---- stage ctx -> sA bf16: 9 pixels x 64 b x 16 k ----
    for (int item = t; item < 9 * 64; item += 256) {
        int p = item >> 6;
        int b = item & 63;
        int di = p / 3 - 1, dj = p % 3 - 1;
        int ni = (in_ + di + HH) & (HH - 1);
        int nj = (jn + dj + WW) & (WW - 1);
        const uint8_t* src = zt + (((size_t)(ni * WW + nj) * BB + (b_base + b)) << 4);
        uint4 raw = *(const uint4*)src;
        const uint8_t* bytes = (const uint8_t*)&raw;
        union { __bf16 h[16]; uint4 q[2]; } u;
#pragma unroll
        for (int k = 0; k < 16; ++k)
            u.h[k] = (__bf16)((float)bytes[k] * (1.0f / 15.0f));
        uint4* dst = (uint4*)(sA + b * APITCH + p * 16);
        dst[0] = u.q[0];
        dst[1] = u.q[1];
    }
    __syncthreads();

    // ---- GEMM1: M=64 x N=128 x K=160, wave owns 32 N-cols, 4 M-tiles ----
    f32x4 acc[4][2] = {};
#pragma unroll
    for (int mt = 0; mt < 4; ++mt) {
        bf16x8 Af[5];
#pragma unroll
        for (int ks = 0; ks < 5; ++ks)
            Af[ks] = *(const bf16x8*)(sA + (mt * 16 + l15) * APITCH + ks * 32 + l4 * 8);
#pragma unroll
        for (int ks = 0; ks < 5; ++ks) {
            acc[mt][0] = __builtin_amdgcn_mfma_f32_16x16x32_bf16(Af[ks], Bf[0][ks], acc[mt][0], 0, 0, 0);
            acc[mt][1] = __builtin_amdgcn_mfma_f32_16x16x32_bf16(Af[ks], Bf[1][ks], acc[mt][1], 0, 0, 0);
        }
    }
    __syncthreads();   // all sA reads done before sH overlay writes

    // ---- bias + relu -> sH bf16 [b][h] ----
#pragma unroll
    for (int mt = 0; mt < 4; ++mt)
#pragma unroll
        for (int nt = 0; nt < 2; ++nt) {
            float bv = nt ? b1v1 : b1v0;
            int hcol = n0 + nt * 16 + l15;
#pragma unroll
            for (int r = 0; r < 4; ++r) {
                int b = mt * 16 + l4 * 4 + r;
                float v = fmaxf(acc[mt][nt][r] + bv, 0.0f);
                sH[b * HPITCH + hcol] = bf16_bits(v);
            }
        }
    __syncthreads();

    // ---- GEMM2: M=64 x N=16 x K=128; wave owns M-tile `wave` ----
    f32x4 acc2 = {};
#pragma unroll
    for (int ks = 0; ks < 4; ++ks) {
        bf16x8 Af = *(const bf16x8*)(sH + (wave * 16 + l15) * HPITCH + ks * 32 + l4 * 8);
        acc2 = __builtin_amdgcn_mfma_f32_16x16x32_bf16(Af, Bf2[ks], acc2, 0, 0, 0);
    }
#pragma unroll
    for (int r = 0; r < 4; ++r) {
        int b = wave * 16 + l4 * 4 + r;
        slg[b * 17 + l15] = acc2[r] + b2v;
    }
    __syncthreads();

    // ---- argmax + compare + ballot (wave 0) ----
    if (t < 64) {
        float best = slg[t * 17];
        int pi = 0;
#pragma unroll
        for (int c = 1; c < CDIM; ++c) {
            float v = slg[t * 17 + c];
            if (v > best) { best = v; pi = c; }   // strict > = first-max (jnp.argmax)
        }
        int tgt = zt[(((size_t)(in_ * WW + jn) * BB + b_base + t) << 4) + sn];
        unsigned long long m = __ballot(pi != tgt);
        if (t == 0) atomicAdd(&counters[0], (int)__popcll(m));
    }
}

__global__ void finalize_kernel(const int* __restrict__ counters, float* __restrict__ out) {
    out[0] = (float)(counters[0]) / (float)(NB * BB);
}

extern "C" void kernel_launch(void* const* d_in, const int* in_sizes, int n_in,
                              void* d_out, int out_size, void* d_ws, size_t ws_size,
                              hipStream_t stream) {
    const int* z = (const int*)d_in[0];
    const int* bs = (const int*)d_in[1];
    const int* ii = (const int*)d_in[2];
    const int* jj = (const int*)d_in[3];
    const float* W1 = (const float*)d_in[4];
    const float* b1 = (const float*)d_in[5];
    const float* W2 = (const float*)d_in[6];
    const float* b2 = (const float*)d_in[7];
    float* out = (float*)d_out;

    uint8_t* ws = (uint8_t*)d_ws;
    int* counters = (int*)ws;
    unsigned short* W1t = (unsigned short*)(ws + W1T_OFF);
    unsigned short* W2b = (unsigned short*)(ws + W2B_OFF);
    uint8_t* zt = ws + ZT_OFF;

    prep_kernel<<<5384, 256, 0, stream>>>(z, W1, W2, zt, W1t, W2b, counters);
    main_kernel<<<NB * 4, 256, 0, stream>>>(zt, W1t, b1, W2b, b2, bs, ii, jj, counters);
    finalize_kernel<<<1, 1, 0, stream>>>(counters, out);
}

// Round 6
// 132.620 us; speedup vs baseline: 1.6768x; 1.2247x over previous
//
#include <hip/hip_runtime.h>
#include <stdint.h>

#define NB 1024
#define BB 256
#define KK 16
#define HH 64
#define WW 64
#define F_FULL 144
#define HDIM 128
#define CDIM 16
#define KPAD 160
#define APITCH 168   // A LDS pitch (bf16): 336 B rows -> 2-way bank alias only (free, m136)
#define HPITCH 136   // h LDS pitch (bf16)
#define ABYTES (64 * APITCH * 2)   // 21504

typedef __bf16 bf16x8 __attribute__((ext_vector_type(8)));
typedef float f32x4 __attribute__((ext_vector_type(4)));

// ---------------- ws layout ----------------
// [0,4)        : int err_count
// [256, ..)    : W1t bf16 [16][128][160]
// [.., ..)     : W2b bf16 [16][128]
// [.., ..)     : zt u8 (H,W,B,K)
#define W1T_OFF 256
#define W1T_BYTES (16 * HDIM * KPAD * 2)
#define W2B_OFF (W1T_OFF + W1T_BYTES)
#define W2B_BYTES (CDIM * HDIM * 2)
#define ZT_OFF (W2B_OFF + W2B_BYTES)

__device__ __forceinline__ unsigned short bf16_bits(float v) {
    __bf16 b = (__bf16)v;
    return __builtin_bit_cast(unsigned short, b);
}

// Fused prep: blocks [0,4096) transpose z -> zt ; [4096,5376) build W1t ;
// [5376,5384) build W2b ; block 5376 t==0 zeroes err counter.
#define TP 144
__global__ __launch_bounds__(256) void prep_kernel(
    const int* __restrict__ z, const float* __restrict__ W1,
    const float* __restrict__ W2, uint8_t* __restrict__ zt,
    unsigned short* __restrict__ W1t, unsigned short* __restrict__ W2b,
    int* __restrict__ counters) {
    int bid = blockIdx.x;
    int t = threadIdx.x;
    if (bid < 4096) {
        __shared__ uint8_t tile[32 * TP];   // tile[c][r], pitch 144
        int bx = bid & 127;                 // c tile
        int by = bid >> 7;                  // r tile, 0..31
        int c0 = bx * 32, r0 = by * 128;
#pragma unroll
        for (int i = 0; i < 4; ++i) {
            int lin = i * 256 + t;
            int c = lin & 31;
            int rq = lin >> 5;
            uchar4 v;
            v.x = (uint8_t)z[(size_t)(r0 + rq * 4 + 0) * 4096 + c0 + c];
            v.y = (uint8_t)z[(size_t)(r0 + rq * 4 + 1) * 4096 + c0 + c];
            v.z = (uint8_t)z[(size_t)(r0 + rq * 4 + 2) * 4096 + c0 + c];
            v.w = (uint8_t)z[(size_t)(r0 + rq * 4 + 3) * 4096 + c0 + c];
            *(uchar4*)(tile + c * TP + rq * 4) = v;
        }
        __syncthreads();
        int cy = t >> 3, rx = t & 7;
        uint4 v = *(const uint4*)(tile + cy * TP + rx * 16);
        *(uint4*)(zt + (size_t)(c0 + cy) * 4096 + r0 + rx * 16) = v;
    } else if (bid < 5376) {
        int idx = (bid - 4096) * 256 + t;   // 16*128*160 = 327680
        int k = idx % KPAD;
        int h = (idx / KPAD) % HDIM;
        int s = idx / (KPAD * HDIM);
        int drop = 4 * KK + s;
        float val = 0.0f;
        if (k < F_FULL && k != drop) {
            int src = k - (k > drop ? 1 : 0);
            val = W1[src * HDIM + h];
        }
        W1t[idx] = bf16_bits(val);
    } else {
        int idx = (bid - 5376) * 256 + t;   // 2048 total
        if (idx < CDIM * HDIM) {
            int k = idx % HDIM;
            int c = idx / HDIM;
            W2b[idx] = bf16_bits(W2[k * CDIM + c]);
        }
        if (bid == 5376 && t == 0) counters[0] = 0;
    }
}

// Main fused MFMA kernel: one block per n; 4 b-tiles of 64, double-buffered
// A staging software-pipelined against compute. LDS: 2 A bufs (sH overlays
// the buffer being computed) + slg -> 47360 B -> 3 blocks/CU.
__global__ __launch_bounds__(256, 3) void main_kernel(
    const uint8_t* __restrict__ zt, const unsigned short* __restrict__ W1t,
    const float* __restrict__ b1, const unsigned short* __restrict__ W2b,
    const float* __restrict__ b2, const int* __restrict__ bs,
    const int* __restrict__ ii, const int* __restrict__ jj,
    int* __restrict__ counters) {
    __shared__ __align__(16) unsigned char smem[2 * ABYTES + 64 * 17 * 4];
    unsigned short* sA0 = (unsigned short*)smem;
    unsigned short* sA1 = (unsigned short*)(smem + ABYTES);
    float* slg = (float*)(smem + 2 * ABYTES);   // [64][17]

    int t = threadIdx.x;
    int n = blockIdx.x;
    int wave = t >> 6, lane = t & 63;
    int l15 = lane & 15, l4 = lane >> 4;

    int in_ = ii[n], jn = jj[n], sn = bs[n];

    // ---- B fragments: once per n (L2-hot) ----
    const unsigned short* w1s = W1t + (size_t)sn * (HDIM * KPAD);
    int n0 = wave * 32;
    bf16x8 Bf[2][5];
#pragma unroll
    for (int nt = 0; nt < 2; ++nt)
#pragma unroll
        for (int ks = 0; ks < 5; ++ks)
            Bf[nt][ks] = *(const bf16x8*)(w1s + (n0 + nt * 16 + l15) * KPAD + ks * 32 + l4 * 8);
    bf16x8 Bf2[4];
#pragma unroll
    for (int ks = 0; ks < 4; ++ks)
        Bf2[ks] = *(const bf16x8*)(W2b + l15 * HDIM + ks * 32 + l4 * 8);
    float b1v0 = b1[n0 + l15], b1v1 = b1[n0 + 16 + l15];
    float b2v = b2[l15];

    // ---- zero A pad k in [144,168) for BOTH buffers ----
    if (t < 192) {
        int b = t / 3, part = t % 3;
        *(uint4*)(sA0 + b * APITCH + F_FULL + part * 8) = make_uint4(0, 0, 0, 0);
        *(uint4*)(sA1 + b * APITCH + F_FULL + part * 8) = make_uint4(0, 0, 0, 0);
    }

    // ---- gather: 576 items (9 pixels x 64 b) per tile; thread t: items t, t+256, (+512 if t<64)
    uint4 g0, g1, g2;
    auto gload = [&](int tile) {
        int b = (t & 63) + tile * 64;
        int p0 = t >> 6;                                  // 0..3
        int ni0 = (in_ + p0 / 3 - 1) & (HH - 1);
        int nj0 = (jn + p0 % 3 - 1) & (WW - 1);
        g0 = *(const uint4*)(zt + (((size_t)(ni0 * WW + nj0) * BB + b) << 4));
        int p1 = p0 + 4;                                  // 4..7
        int ni1 = (in_ + p1 / 3 - 1) & (HH - 1);
        int nj1 = (jn + p1 % 3 - 1) & (WW - 1);
        g1 = *(const uint4*)(zt + (((size_t)(ni1 * WW + nj1) * BB + b) << 4));
        if (t < 64) {                                     // p=8 -> di=+1, dj=+1
            int ni2 = (in_ + 1) & (HH - 1);
            int nj2 = (jn + 1) & (WW - 1);
            g2 = *(const uint4*)(zt + (((size_t)(ni2 * WW + nj2) * BB + b) << 4));
        }
    };
    auto gwrite = [&](unsigned short* dst) {
        int b = t & 63;
        int p0 = t >> 6;
        auto conv = [&](uint4 raw, int p) {
            const uint8_t* bytes = (const uint8_t*)&raw;
            union { __bf16 h[16]; uint4 q[2]; } u;
#pragma unroll
            for (int k = 0; k < 16; ++k)
                u.h[k] = (__bf16)((float)bytes[k] * (1.0f / 15.0f));
            uint4* d = (uint4*)(dst + b * APITCH + p * 16);
            d[0] = u.q[0];
            d[1] = u.q[1];
        };
        conv(g0, p0);
        conv(g1, p0 + 4);
        if (t < 64) conv(g2, 8);
    };

    gload(0);
    gwrite(sA0);
    int local_err = 0;

    for (int tile = 0; tile < 4; ++tile) {
        unsigned short* sA = (tile & 1) ? sA1 : sA0;
        unsigned short* sH = sA;                    // overlay after GEMM1 reads done
        unsigned short* sAnext = (tile & 1) ? sA0 : sA1;

        if (tile < 3) gload(tile + 1);              // loads in flight across compute
        __syncthreads();                            // sA staging complete

        // ---- GEMM1: M=64 x N=128 x K=160, wave owns 32 N-cols, 4 M-tiles ----
        f32x4 acc[4][2] = {};
#pragma unroll
        for (int mt = 0; mt < 4; ++mt) {
            bf16x8 Af[5];
#pragma unroll
            for (int ks = 0; ks < 5; ++ks)
                Af[ks] = *(const bf16x8*)(sA + (mt * 16 + l15) * APITCH + ks * 32 + l4 * 8);
#pragma unroll
            for (int ks = 0; ks < 5; ++ks) {
                acc[mt][0] = __builtin_amdgcn_mfma_f32_16x16x32_bf16(Af[ks], Bf[0][ks], acc[mt][0], 0, 0, 0);
                acc[mt][1] = __builtin_amdgcn_mfma_f32_16x16x32_bf16(Af[ks], Bf[1][ks], acc[mt][1], 0, 0, 0);
            }
        }
        __syncthreads();   // all sA reads done before sH overlay writes

        // ---- bias + relu -> sH bf16 [b][h] ----
#pragma unroll
        for (int mt = 0; mt < 4; ++mt)
#pragma unroll
            for (int nt = 0; nt < 2; ++nt) {
                float bv = nt ? b1v1 : b1v0;
                int hcol = n0 + nt * 16 + l15;
#pragma unroll
                for (int r = 0; r < 4; ++r) {
                    int b = mt * 16 + l4 * 4 + r;
                    float v = fmaxf(acc[mt][nt][r] + bv, 0.0f);
                    sH[b * HPITCH + hcol] = bf16_bits(v);
                }
            }
        __syncthreads();

        // ---- GEMM2: M=64 x N=16 x K=128; wave owns M-tile `wave` ----
        f32x4 acc2 = {};
#pragma unroll
        for (int ks = 0; ks < 4; ++ks) {
            bf16x8 Af = *(const bf16x8*)(sH + (wave * 16 + l15) * HPITCH + ks * 32 + l4 * 8);
            acc2 = __builtin_amdgcn_mfma_f32_16x16x32_bf16(Af, Bf2[ks], acc2, 0, 0, 0);
        }
#pragma unroll
        for (int r = 0; r < 4; ++r) {
            int b = wave * 16 + l4 * 4 + r;
            slg[b * 17 + l15] = acc2[r] + b2v;
        }
        __syncthreads();

        // ---- argmax + compare (wave 0); stage next tile concurrently ----
        if (t < 64) {
            float best = slg[t * 17];
            int pi = 0;
#pragma unroll
            for (int c = 1; c < CDIM; ++c) {
                float v = slg[t * 17 + c];
                if (v > best) { best = v; pi = c; }   // strict > = first-max (jnp.argmax)
            }
            int bglob = tile * 64 + t;
            int tgt = zt[(((size_t)(in_ * WW + jn) * BB + bglob) << 4) + sn];
            unsigned long long m = __ballot(pi != tgt);
            if (t == 0) local_err += (int)__popcll(m);
        }
        if (tile < 3) gwrite(sAnext);   // waits vmcnt here, not earlier
    }

    if (t == 0) atomicAdd(&counters[0], local_err);
}

__global__ void finalize_kernel(const int* __restrict__ counters, float* __restrict__ out) {
    out[0] = (float)(counters[0]) / (float)(NB * BB);
}

extern "C" void kernel_launch(void* const* d_in, const int* in_sizes, int n_in,
                              void* d_out, int out_size, void* d_ws, size_t ws_size,
                              hipStream_t stream) {
    const int* z = (const int*)d_in[0];
    const int* bs = (const int*)d_in[1];
    const int* ii = (const int*)d_in[2];
    const int* jj = (const int*)d_in[3];
    const float* W1 = (const float*)d_in[4];
    const float* b1 = (const float*)d_in[5];
    const float* W2 = (const float*)d_in[6];
    const float* b2 = (const float*)d_in[7];
    float* out = (float*)d_out;

    uint8_t* ws = (uint8_t*)d_ws;
    int* counters = (int*)ws;
    unsigned short* W1t = (unsigned short*)(ws + W1T_OFF);
    unsigned short* W2b = (unsigned short*)(ws + W2B_OFF);
    uint8_t* zt = ws + ZT_OFF;

    prep_kernel<<<5384, 256, 0, stream>>>(z, W1, W2, zt, W1t, W2b, counters);
    main_kernel<<<NB, 256, 0, stream>>>(zt, W1t, b1, W2b, b2, bs, ii, jj, counters);
    finalize_kernel<<<1, 1, 0, stream>>>(counters, out);
}